// Round 4
// baseline (307.604 us; speedup 1.0000x reference)
//
#include <hip/hip_runtime.h>
#include <hip/hip_bf16.h>

#define B_ 4
#define S_ 128
#define D_ 512
#define H_ 8
#define DH_ 64
#define F_ 2048
#define R_ 8
#define BS_ (B_ * S_)
#define BSD_ (BS_ * D_)
#define E_ 262144          // 512*512

typedef __attribute__((ext_vector_type(8))) short short8;
typedef __attribute__((ext_vector_type(4))) float f32x4;
typedef __attribute__((ext_vector_type(4))) unsigned short ushort4v;

// fp32 -> bf16 hi (RNE) + bf16 lo (RNE of exact residual)
__device__ __forceinline__ void split2(float a, unsigned short& h, unsigned short& l) {
    unsigned u = __float_as_uint(a);
    unsigned hr = (u + 0x7FFFu + ((u >> 16) & 1u)) >> 16;
    h = (unsigned short)hr;
    float lo = a - __uint_as_float(hr << 16);
    unsigned u2 = __float_as_uint(lo);
    l = (unsigned short)((u2 + 0x7FFFu + ((u2 >> 16) & 1u)) >> 16);
}

// ---------------- prep: weight transpose+split (blocks < nt) + LN1 (rest) ----------------
struct TDesc { const float* s; unsigned short* h; unsigned short* l; int K; int N; int off; };
struct TPack { TDesc d[10]; };

__global__ void prep_kernel(TPack p, int nt, const float* __restrict__ x,
                            const float* __restrict__ g, const float* __restrict__ be,
                            unsigned short* __restrict__ xh, unsigned short* __restrict__ xl) {
    __shared__ float tr[32][33];
    __shared__ float red[256];
    int bid = blockIdx.x;
    if (bid < nt) {
        int wi = 0;
#pragma unroll
        for (int i = 1; i < 10; ++i) if (bid >= p.d[i].off) wi = i;
        const TDesc dd = p.d[wi];
        int t = bid - dd.off;
        int ntk = dd.K / 32;
        int tk = t % ntk, tn = t / ntk;
        int k0 = tk * 32, n0 = tn * 32;
        int col = threadIdx.x & 31, rg = threadIdx.x >> 5;   // rg 0..7
#pragma unroll
        for (int i = 0; i < 4; ++i) {
            int row = rg * 4 + i;
            tr[row][col] = dd.s[(size_t)(k0 + row) * dd.N + n0 + col];
        }
        __syncthreads();
#pragma unroll
        for (int i = 0; i < 4; ++i) {
            int n = n0 + rg * 4 + i;
            int k = k0 + col;
            unsigned short h, l;
            split2(tr[col][rg * 4 + i], h, l);
            dd.h[(size_t)n * dd.K + k] = h;
            dd.l[(size_t)n * dd.K + k] = l;
        }
    } else {
        int row = bid - nt;
        int t = threadIdx.x;
        const float* xr = x + (size_t)row * D_;
        float v0 = xr[t], v1 = xr[t + 256];
        red[t] = v0 + v1;
        __syncthreads();
        for (int off = 128; off > 0; off >>= 1) { if (t < off) red[t] += red[t + off]; __syncthreads(); }
        float mean = red[0] * (1.0f / D_);
        __syncthreads();
        float d0 = v0 - mean, d1 = v1 - mean;
        red[t] = d0 * d0 + d1 * d1;
        __syncthreads();
        for (int off = 128; off > 0; off >>= 1) { if (t < off) red[t] += red[t + off]; __syncthreads(); }
        float rs = rsqrtf(red[0] * (1.0f / D_) + 1e-5f);
        float o0 = d0 * rs * g[t] + be[t];
        float o1 = d1 * rs * g[t + 256] + be[t + 256];
        unsigned short h, l;
        split2(o0, h, l); xh[(size_t)row * D_ + t] = h;       xl[(size_t)row * D_ + t] = l;
        split2(o1, h, l); xh[(size_t)row * D_ + t + 256] = h; xl[(size_t)row * D_ + t + 256] = l;
    }
}

// ---------------- MFMA bf16x3 GEMM core: direct-global fragments, no LDS, no barriers ----------------
// Fragment addressing identical to prior LDS layout => bit-identical accumulation order.
__device__ __forceinline__ void mgemm_core(const unsigned short* __restrict__ Ath,
                                           const unsigned short* __restrict__ Atl,
                                           const unsigned short* __restrict__ Bth,
                                           const unsigned short* __restrict__ Btl,
                                           int K, int rowBase, int colBase,
                                           int kStart, int nsteps,
                                           f32x4 acc[2][2]) {
    int tid = threadIdx.x;
    int w = tid >> 6, lane = tid & 63;
    int lm = lane & 15, quad = lane >> 4;
    int wm = (w & 1) * 32, wn = (w >> 1) * 32;
    size_t aoff = (size_t)(rowBase + wm + lm) * K + kStart + quad * 8;
    size_t boff = (size_t)(colBase + wn + lm) * K + kStart + quad * 8;
    const size_t rstep = (size_t)16 * K;
    short8 ah[2], al[2], bh[2], bl[2];
#pragma unroll
    for (int t = 0; t < 2; ++t) {
        ah[t] = *(const short8*)&Ath[aoff + t * rstep];
        al[t] = *(const short8*)&Atl[aoff + t * rstep];
        bh[t] = *(const short8*)&Bth[boff + t * rstep];
        bl[t] = *(const short8*)&Btl[boff + t * rstep];
    }
    for (int s = 0; s < nsteps; ++s) {
        short8 nah[2], nal[2], nbh[2], nbl[2];
        if (s + 1 < nsteps) {       // prefetch next k-step; latency hides under MFMAs
            size_t ao = aoff + (size_t)(s + 1) * 32;
            size_t bo = boff + (size_t)(s + 1) * 32;
#pragma unroll
            for (int t = 0; t < 2; ++t) {
                nah[t] = *(const short8*)&Ath[ao + t * rstep];
                nal[t] = *(const short8*)&Atl[ao + t * rstep];
                nbh[t] = *(const short8*)&Bth[bo + t * rstep];
                nbl[t] = *(const short8*)&Btl[bo + t * rstep];
            }
        }
#pragma unroll
        for (int tm = 0; tm < 2; ++tm)
#pragma unroll
            for (int tn = 0; tn < 2; ++tn) {
                acc[tm][tn] = __builtin_amdgcn_mfma_f32_16x16x32_bf16(ah[tm], bh[tn], acc[tm][tn], 0, 0, 0);
                acc[tm][tn] = __builtin_amdgcn_mfma_f32_16x16x32_bf16(ah[tm], bl[tn], acc[tm][tn], 0, 0, 0);
                acc[tm][tn] = __builtin_amdgcn_mfma_f32_16x16x32_bf16(al[tm], bh[tn], acc[tm][tn], 0, 0, 0);
            }
        if (s + 1 < nsteps) {
#pragma unroll
            for (int t = 0; t < 2; ++t) {
                ah[t] = nah[t]; al[t] = nal[t]; bh[t] = nbh[t]; bl[t] = nbl[t];
            }
        }
    }
}

// Generic GEMM: optional fp32 out, optional pre-split bf16 h/l out.
__global__ __launch_bounds__(256) void mgemm_kernel(const unsigned short* __restrict__ Ath,
                                                    const unsigned short* __restrict__ Atl,
                                                    const unsigned short* __restrict__ Bth,
                                                    const unsigned short* __restrict__ Btl,
                                                    const float* __restrict__ bias,
                                                    float* __restrict__ Cf,
                                                    unsigned short* __restrict__ Ch,
                                                    unsigned short* __restrict__ Cl,
                                                    int N, int K, int relu) {
    int tid = threadIdx.x;
    int w = tid >> 6, lane = tid & 63;
    int lm = lane & 15, quad = lane >> 4;
    int wm = (w & 1) * 32, wn = (w >> 1) * 32;
    int rowBase = blockIdx.y * 64, colBase = blockIdx.x * 64;
    f32x4 acc[2][2] = {};
    mgemm_core(Ath, Atl, Bth, Btl, K, rowBase, colBase, 0, K / 32, acc);
#pragma unroll
    for (int tm = 0; tm < 2; ++tm)
#pragma unroll
        for (int tn = 0; tn < 2; ++tn) {
            int col = colBase + wn + tn * 16 + lm;
            float bi = bias ? bias[col] : 0.f;
#pragma unroll
            for (int r = 0; r < 4; ++r) {
                int row = rowBase + wm + tm * 16 + quad * 4 + r;
                float v = acc[tm][tn][r] + bi;
                if (relu) v = fmaxf(v, 0.f);
                size_t o = (size_t)row * N + col;
                if (Cf) Cf[o] = v;
                if (Ch) {
                    unsigned short sh, sl;
                    split2(v, sh, sl);
                    Ch[o] = sh; Cl[o] = sl;
                }
            }
        }
}

// z-batched GEMM over weight slabs (QKV: 3, rc halves: 2); fp32 out only.
__global__ __launch_bounds__(256) void mgemm_zw_kernel(const unsigned short* __restrict__ Ath,
                                                       const unsigned short* __restrict__ Atl,
                                                       const unsigned short* __restrict__ Bth,
                                                       const unsigned short* __restrict__ Btl,
                                                       const float* __restrict__ b0,
                                                       const float* __restrict__ b1,
                                                       const float* __restrict__ b2,
                                                       float* __restrict__ Cbase,
                                                       int M, int N, int K) {
    int z = blockIdx.z;
    const unsigned short* bth = Bth + (size_t)z * K * N;
    const unsigned short* btl = Btl + (size_t)z * K * N;
    const float* bias = (z == 0) ? b0 : (z == 1) ? b1 : b2;
    float* C = Cbase + (size_t)z * M * N;
    int tid = threadIdx.x;
    int w = tid >> 6, lane = tid & 63;
    int lm = lane & 15, quad = lane >> 4;
    int wm = (w & 1) * 32, wn = (w >> 1) * 32;
    int rowBase = blockIdx.y * 64, colBase = blockIdx.x * 64;
    f32x4 acc[2][2] = {};
    mgemm_core(Ath, Atl, bth, btl, K, rowBase, colBase, 0, K / 32, acc);
#pragma unroll
    for (int tm = 0; tm < 2; ++tm)
#pragma unroll
        for (int tn = 0; tn < 2; ++tn) {
            int col = colBase + wn + tn * 16 + lm;
            float bi = bias ? bias[col] : 0.f;
#pragma unroll
            for (int r = 0; r < 4; ++r) {
                int row = rowBase + wm + tm * 16 + quad * 4 + r;
                C[(size_t)row * N + col] = acc[tm][tn][r] + bi;
            }
        }
}

// split-K partial GEMM: each z-slice writes its own fp32 slab (no atomics).
__global__ __launch_bounds__(256) void mgemm_part_kernel(const unsigned short* __restrict__ Ath,
                                                         const unsigned short* __restrict__ Atl,
                                                         const unsigned short* __restrict__ Bth,
                                                         const unsigned short* __restrict__ Btl,
                                                         float* __restrict__ Cbase,
                                                         int M, int N, int K) {
    int ks = gridDim.z, z = blockIdx.z;
    int kLen = K / ks, kStart = z * kLen;
    float* C = Cbase + (size_t)z * M * N;
    int tid = threadIdx.x;
    int w = tid >> 6, lane = tid & 63;
    int lm = lane & 15, quad = lane >> 4;
    int wm = (w & 1) * 32, wn = (w >> 1) * 32;
    int rowBase = blockIdx.y * 64, colBase = blockIdx.x * 64;
    f32x4 acc[2][2] = {};
    mgemm_core(Ath, Atl, Bth, Btl, K, rowBase, colBase, kStart, kLen / 32, acc);
#pragma unroll
    for (int tm = 0; tm < 2; ++tm)
#pragma unroll
        for (int tn = 0; tn < 2; ++tn) {
            int col = colBase + wn + tn * 16 + lm;
#pragma unroll
            for (int r = 0; r < 4; ++r) {
                int row = rowBase + wm + tm * 16 + quad * 4 + r;
                C[(size_t)row * N + col] = acc[tm][tn][r];
            }
        }
}

// sum 4 partials + bias -> nu fp32 + bf16 h/l
__global__ void reduce4_kernel(const float* __restrict__ part, const float* __restrict__ b2,
                               float* __restrict__ nu,
                               unsigned short* __restrict__ nh, unsigned short* __restrict__ nl) {
    int base = blockIdx.x * 1024 + threadIdx.x * 4;
    f32x4 s = *(const f32x4*)&b2[base & (D_ - 1)];
#pragma unroll
    for (int z = 0; z < 4; ++z) s += *(const f32x4*)&part[(size_t)z * BSD_ + base];
    *(f32x4*)&nu[base] = s;
    ushort4v hv, lv;
#pragma unroll
    for (int i = 0; i < 4; ++i) { unsigned short h, l; split2(s[i], h, l); hv[i] = h; lv[i] = l; }
    *(ushort4v*)&nh[base] = hv;
    *(ushort4v*)&nl[base] = lv;
}

// reasoned = nu + sum 8 partials -> bf16 h/l only
__global__ void reduce8_kernel(const float* __restrict__ part, const float* __restrict__ nu,
                               unsigned short* __restrict__ rh, unsigned short* __restrict__ rl) {
    int base = blockIdx.x * 1024 + threadIdx.x * 4;
    f32x4 s = *(const f32x4*)&nu[base];
#pragma unroll
    for (int z = 0; z < 8; ++z) s += *(const f32x4*)&part[(size_t)z * BSD_ + base];
    ushort4v hv, lv;
#pragma unroll
    for (int i = 0; i < 4; ++i) { unsigned short h, l; split2(s[i], h, l); hv[i] = h; lv[i] = l; }
    *(ushort4v*)&rh[base] = hv;
    *(ushort4v*)&rl[base] = lv;
}

// ---------------- Fused attention + adjacency: one block per (b,i), 8 waves = 8 heads ----------------
__global__ __launch_bounds__(512) void attn_fused_kernel(const float* __restrict__ q,
                                                         const float* __restrict__ k,
                                                         const float* __restrict__ v,
                                                         unsigned short* __restrict__ ch,
                                                         unsigned short* __restrict__ cl,
                                                         int* __restrict__ ecount,
                                                         int* __restrict__ elist) {
    __shared__ float qsm[H_][DH_];
    __shared__ float psm[H_][S_];
    int h = threadIdx.x >> 6, lane = threadIdx.x & 63;
    int blk = blockIdx.x;                 // b*S + i
    int i = blk & (S_ - 1);
    int b = blk >> 7;
    const float* qrow = q + (size_t)(b * S_ + i) * D_ + h * DH_;
    qsm[h][lane] = qrow[lane];
    __syncthreads();
    // two scores per lane: j = lane, lane+64
    float s0 = 0.f, s1 = 0.f;
    const float* k0p = k + (size_t)(b * S_ + lane) * D_ + h * DH_;
    const float* k1p = k0p + (size_t)64 * D_;
#pragma unroll 8
    for (int d = 0; d < DH_; ++d) {
        float qd = qsm[h][d];
        s0 += qd * k0p[d];
        s1 += qd * k1p[d];
    }
    s0 *= 0.125f; s1 *= 0.125f;
    float m = fmaxf(s0, s1);
#pragma unroll
    for (int off = 32; off > 0; off >>= 1) m = fmaxf(m, __shfl_xor(m, off));
    float e0 = __expf(s0 - m), e1 = __expf(s1 - m);
    float sum = e0 + e1;
#pragma unroll
    for (int off = 32; off > 0; off >>= 1) sum += __shfl_xor(sum, off);
    float inv = 1.f / sum;
    psm[h][lane] = e0 * inv;
    psm[h][lane + 64] = e1 * inv;
    __syncthreads();
    // adjacency: threads 0..127 handle j = tid
    if (threadIdx.x < S_) {
        int j = threadIdx.x;
        float s = 0.f;
#pragma unroll
        for (int hh = 0; hh < H_; ++hh) s += psm[hh][j];
        s *= (1.0f / H_);
        if (s > 0.1f && i != j) {
            int p = atomicAdd(ecount, 1);
            elist[p] = blk * S_ + j;
        }
    }
    // ctx: lane = d within this head
    const float* vbase = v + (size_t)b * S_ * D_ + h * DH_ + lane;
    float acc = 0.f;
    for (int j = 0; j < S_; ++j) acc += psm[h][j] * vbase[(size_t)j * D_];
    unsigned short sh, sl;
    split2(acc, sh, sl);
    size_t o = (size_t)(b * S_ + i) * D_ + h * DH_ + lane;
    ch[o] = sh; cl[o] = sl;
}

// ---------------- Relation classifier over compacted edges (4 edge-waves per block) ----------------
__global__ __launch_bounds__(256) void edge_kernel(const float* __restrict__ a_part,
                                                   const float* __restrict__ b_part,
                                                   const float* __restrict__ rc_b1,
                                                   const float* __restrict__ rc_w2,
                                                   const float* __restrict__ rc_b2,
                                                   const int* __restrict__ elist,
                                                   const int* __restrict__ ecount,
                                                   int* __restrict__ rel) {
    int w = threadIdx.x >> 6, lane = threadIdx.x & 63;
    int n = *ecount;
    for (int e = blockIdx.x * 4 + w; e < n; e += gridDim.x * 4) {
        int idx = elist[e];
        int vv = idx & (S_ - 1);
        int bu = idx >> 7;
        int u = bu & (S_ - 1);
        int b = bu >> 7;
        const float* ap = a_part + (size_t)(b * S_ + u) * D_;
        const float* bp = b_part + (size_t)(b * S_ + vv) * D_;
        float lp[R_];
#pragma unroll
        for (int r = 0; r < R_; ++r) lp[r] = 0.f;
#pragma unroll
        for (int jj = 0; jj < D_ / 64; ++jj) {
            int d = lane + jj * 64;
            float hv = fmaxf(ap[d] + bp[d] + rc_b1[d], 0.f);
#pragma unroll
            for (int r = 0; r < R_; ++r) lp[r] += hv * rc_w2[d * R_ + r];
        }
#pragma unroll
        for (int r = 0; r < R_; ++r) {
#pragma unroll
            for (int off = 32; off > 0; off >>= 1) lp[r] += __shfl_down(lp[r], off);
        }
        if (lane == 0) {
            float best = lp[0] + rc_b2[0];
            int bi = 0;
#pragma unroll
            for (int r = 1; r < R_; ++r) {
                float L = lp[r] + rc_b2[r];
                if (L > best) { best = L; bi = r; }
            }
            rel[idx] = bi;
        }
    }
}

// ---------------- mbuild: LDS accumulate, pre-split write ----------------
__global__ __launch_bounds__(128) void mbuild_kernel(const float* __restrict__ nu,
                                                     const int* __restrict__ rel,
                                                     unsigned short* __restrict__ Mh,
                                                     unsigned short* __restrict__ Ml) {
    __shared__ float acc[R_ * D_];   // 16 KB
    __shared__ int rl[S_];
    int blk = blockIdx.x;            // b*S + v
    int vv = blk & (S_ - 1);
    int b = blk >> 7;
    int t = threadIdx.x;             // 128
    for (int i = t; i < R_ * D_; i += 128) acc[i] = 0.f;
    rl[t] = rel[((size_t)b * S_ + t) * S_ + vv];
    __syncthreads();
    for (int u = 0; u < S_; ++u) {
        int r = rl[u];
        if (r > 0) {
            const float* nurow = nu + (size_t)(b * S_ + u) * D_;
            float* arow = acc + r * D_;
#pragma unroll
            for (int jj = 0; jj < D_ / 128; ++jj) arow[t + jj * 128] += nurow[t + jj * 128];
        }
    }
    __syncthreads();
    unsigned short* Hrow = Mh + (size_t)blk * (R_ * D_);
    unsigned short* Lrow = Ml + (size_t)blk * (R_ * D_);
    for (int i = t; i < R_ * D_; i += 128) {
        unsigned short sh, sl;
        split2(acc[i], sh, sl);
        Hrow[i] = sh; Lrow[i] = sl;
    }
}

// ---------------- LayerNorm 2 -> fp32 out ----------------
__global__ void ln2_kernel(const float* __restrict__ x, const float* __restrict__ y,
                           const float* __restrict__ g, const float* __restrict__ be,
                           float* __restrict__ out) {
    int row = blockIdx.x;
    int t = threadIdx.x;
    __shared__ float red[256];
    float v0 = x[row * D_ + t]       + y[row * D_ + t];
    float v1 = x[row * D_ + t + 256] + y[row * D_ + t + 256];
    red[t] = v0 + v1;
    __syncthreads();
    for (int off = 128; off > 0; off >>= 1) {
        if (t < off) red[t] += red[t + off];
        __syncthreads();
    }
    float mean = red[0] * (1.0f / D_);
    __syncthreads();
    float d0 = v0 - mean, d1 = v1 - mean;
    red[t] = d0 * d0 + d1 * d1;
    __syncthreads();
    for (int off = 128; off > 0; off >>= 1) {
        if (t < off) red[t] += red[t + off];
        __syncthreads();
    }
    float rs = rsqrtf(red[0] * (1.0f / D_) + 1e-5f);
    out[row * D_ + t]       = d0 * rs * g[t]       + be[t];
    out[row * D_ + t + 256] = d1 * rs * g[t + 256] + be[t + 256];
}

extern "C" void kernel_launch(void* const* d_in, const int* in_sizes, int n_in,
                              void* d_out, int out_size, void* d_ws, size_t ws_size,
                              hipStream_t stream) {
    const float* x     = (const float*)d_in[0];
    const float* ln1_g = (const float*)d_in[1];
    const float* ln1_b = (const float*)d_in[2];
    const float* wq    = (const float*)d_in[3];
    const float* bq    = (const float*)d_in[4];
    const float* wk    = (const float*)d_in[5];
    const float* bk    = (const float*)d_in[6];
    const float* wv    = (const float*)d_in[7];
    const float* bv    = (const float*)d_in[8];
    const float* wo    = (const float*)d_in[9];
    const float* bo    = (const float*)d_in[10];
    const float* w1    = (const float*)d_in[11];
    const float* b1    = (const float*)d_in[12];
    const float* w2    = (const float*)d_in[13];
    const float* b2    = (const float*)d_in[14];
    const float* rc_w1 = (const float*)d_in[15];
    const float* rc_b1 = (const float*)d_in[16];
    const float* rc_w2 = (const float*)d_in[17];
    const float* rc_b2 = (const float*)d_in[18];
    const float* kg_w  = (const float*)d_in[19];
    const float* s2n_w = (const float*)d_in[20];
    const float* s2n_b = (const float*)d_in[21];
    const float* ln2_g = (const float*)d_in[22];
    const float* ln2_b = (const float*)d_in[23];
    float* out = (float*)d_out;

    const int BS  = BS_;              // 512
    const int BSD = BSD_;             // 262144

    // ---- Workspace layout ----
    unsigned short* wt = (unsigned short*)d_ws;
    unsigned short* qkv_h = wt;
    unsigned short* qkv_l = wt + 3 * E_;
    unsigned short* wo_h  = wt + 6 * E_;
    unsigned short* wo_l  = wt + 7 * E_;
    unsigned short* w1_h  = wt + 8 * E_;
    unsigned short* w1_l  = wt + 12 * E_;
    unsigned short* w2_h  = wt + 16 * E_;
    unsigned short* w2_l  = wt + 20 * E_;
    unsigned short* rc_h  = wt + 24 * E_;
    unsigned short* rc_l  = wt + 26 * E_;
    unsigned short* kg_h  = wt + 28 * E_;
    unsigned short* kg_l  = wt + 36 * E_;
    unsigned short* s2_h  = wt + 44 * E_;
    unsigned short* s2_l  = wt + 45 * E_;

    // activation bf16 h/l buffers
    unsigned short* xn_h  = wt + 46 * E_;
    unsigned short* xn_l  = xn_h + BSD;
    unsigned short* ctx_h = xn_l + BSD;
    unsigned short* ctx_l = ctx_h + BSD;
    unsigned short* ao_h  = ctx_l + BSD;
    unsigned short* ao_l  = ao_h + BSD;
    unsigned short* hid_h = ao_l + BSD;              // BS*F
    unsigned short* hid_l = hid_h + (size_t)BS * F_;
    unsigned short* nu_h  = hid_l + (size_t)BS * F_;
    unsigned short* nu_l  = nu_h + BSD;
    unsigned short* mb_h  = nu_l + BSD;              // BS*R*D
    unsigned short* mb_l  = mb_h + (size_t)BS * R_ * D_;
    unsigned short* rs_h  = mb_l + (size_t)BS * R_ * D_;
    unsigned short* rs_l  = rs_h + BSD;

    float* fbase  = (float*)(rs_l + BSD);
    float* q      = fbase;                           // q,k,v slabs (3*BSD)
    float* v_     = q + 2 * BSD;
    float* apart  = q + 3 * BSD;                     // a_part,b_part
    float* nu     = apart + 2 * BSD;
    float* y      = nu + BSD;
    float* part4  = y + BSD;                         // 4*BSD
    float* part8  = part4 + 4 * BSD;                 // 8*BSD

    int* rel    = (int*)(part8 + 8 * BSD);
    int* ecount = rel + B_ * S_ * S_;
    int* elist  = ecount + 64;

    // 0a. zero rel + ecount
    hipMemsetAsync(rel, 0, (size_t)(B_ * S_ * S_ + 64) * 4, stream);
    // 0b. transpose+split all weights + LN1 (fused)
    TPack tp;
    int off = 0;
    auto setd = [&](int i, const float* s, unsigned short* h, unsigned short* l, int K, int N) {
        tp.d[i] = TDesc{s, h, l, K, N, off};
        off += (K / 32) * (N / 32);
    };
    setd(0, wq, qkv_h,          qkv_l,          D_, D_);
    setd(1, wk, qkv_h + E_,     qkv_l + E_,     D_, D_);
    setd(2, wv, qkv_h + 2 * E_, qkv_l + 2 * E_, D_, D_);
    setd(3, wo, wo_h, wo_l, D_, D_);
    setd(4, w1, w1_h, w1_l, D_, F_);
    setd(5, w2, w2_h, w2_l, F_, D_);
    setd(6, rc_w1,            rc_h,      rc_l,      D_, D_);
    setd(7, rc_w1 + D_ * D_,  rc_h + E_, rc_l + E_, D_, D_);
    setd(8, kg_w, kg_h, kg_l, R_ * D_, D_);
    setd(9, s2n_w, s2_h, s2_l, D_, D_);
    hipLaunchKernelGGL(prep_kernel, dim3(off + BS), dim3(256), 0, stream, tp, off,
                       x, ln1_g, ln1_b, xn_h, xn_l);

    // 2. QKV (z-batched) -> q,k,v fp32
    hipLaunchKernelGGL(mgemm_zw_kernel, dim3(D_ / 64, BS / 64, 3), dim3(256), 0, stream,
                       xn_h, xn_l, qkv_h, qkv_l, bq, bk, bv, q, BS, D_, D_);
    // 3. attention + adjacency (fused) -> ctx h/l, elist
    hipLaunchKernelGGL(attn_fused_kernel, dim3(BS), dim3(512), 0, stream,
                       q, q + BSD, v_, ctx_h, ctx_l, ecount, elist);
    // 5. wo: ctx -> attn_out h/l
    hipLaunchKernelGGL(mgemm_kernel, dim3(D_ / 64, BS / 64), dim3(256), 0, stream,
                       ctx_h, ctx_l, wo_h, wo_l, bo, (float*)nullptr, ao_h, ao_l, D_, D_, 0);
    // 6. FFN1 (relu): attn_out -> hidden h/l
    hipLaunchKernelGGL(mgemm_kernel, dim3(F_ / 64, BS / 64), dim3(256), 0, stream,
                       ao_h, ao_l, w1_h, w1_l, b1, (float*)nullptr, hid_h, hid_l, F_, D_, 1);
    // 7. FFN2 split-K=4 partials
    hipLaunchKernelGGL(mgemm_part_kernel, dim3(D_ / 64, BS / 64, 4), dim3(256), 0, stream,
                       hid_h, hid_l, w2_h, w2_l, part4, BS, D_, F_);
    // 7b. reduce + bias -> nu fp32 + h/l
    hipLaunchKernelGGL(reduce4_kernel, dim3(BSD / 1024), dim3(256), 0, stream,
                       part4, b2, nu, nu_h, nu_l);
    // 8. rc halves (z-batched) -> a_part,b_part fp32
    hipLaunchKernelGGL(mgemm_zw_kernel, dim3(D_ / 64, BS / 64, 2), dim3(256), 0, stream,
                       nu_h, nu_l, rc_h, rc_l, (const float*)nullptr, (const float*)nullptr,
                       (const float*)nullptr, apart, BS, D_, D_);
    // 9. edges (persistent over compacted list)
    hipLaunchKernelGGL(edge_kernel, dim3(256), dim3(256), 0, stream,
                       apart, apart + BSD, rc_b1, rc_w2, rc_b2, elist, ecount, rel);
    // 10. RGCN aggregate -> Mbuf h/l
    hipLaunchKernelGGL(mbuild_kernel, dim3(BS), dim3(128), 0, stream, nu, rel, mb_h, mb_l);
    // 11. Mbuf @ kg_w split-K=8 partials
    hipLaunchKernelGGL(mgemm_part_kernel, dim3(D_ / 64, BS / 64, 8), dim3(256), 0, stream,
                       mb_h, mb_l, kg_h, kg_l, part8, BS, D_, R_ * D_);
    // 11b. reduce + residual (nu) -> reasoned h/l
    hipLaunchKernelGGL(reduce8_kernel, dim3(BSD / 1024), dim3(256), 0, stream,
                       part8, nu, rs_h, rs_l);
    // 13. s2n: reasoned -> y fp32
    hipLaunchKernelGGL(mgemm_kernel, dim3(D_ / 64, BS / 64), dim3(256), 0, stream,
                       rs_h, rs_l, s2_h, s2_l, s2n_b, y, (unsigned short*)nullptr,
                       (unsigned short*)nullptr, D_, D_, 0);
    // 14. LN2 -> out
    hipLaunchKernelGGL(ln2_kernel, dim3(BS), dim3(256), 0, stream, x, y, ln2_g, ln2_b, out);
}

// Round 5
// 251.343 us; speedup vs baseline: 1.2238x; 1.2238x over previous
//
#include <hip/hip_runtime.h>
#include <hip/hip_bf16.h>

#define B_ 4
#define S_ 128
#define D_ 512
#define H_ 8
#define DH_ 64
#define F_ 2048
#define R_ 8
#define BS_ (B_ * S_)
#define BSD_ (BS_ * D_)
#define E_ 262144          // 512*512

typedef __attribute__((ext_vector_type(8))) short short8;
typedef __attribute__((ext_vector_type(4))) float f32x4;
typedef __attribute__((ext_vector_type(4))) unsigned short ushort4v;

// fp32 -> bf16 hi (RNE) + bf16 lo (RNE of exact residual)
__device__ __forceinline__ void split2(float a, unsigned short& h, unsigned short& l) {
    unsigned u = __float_as_uint(a);
    unsigned hr = (u + 0x7FFFu + ((u >> 16) & 1u)) >> 16;
    h = (unsigned short)hr;
    float lo = a - __uint_as_float(hr << 16);
    unsigned u2 = __float_as_uint(lo);
    l = (unsigned short)((u2 + 0x7FFFu + ((u2 >> 16) & 1u)) >> 16);
}

// ---------------- prep: weight transpose+split (blocks < nt) + LN1 (rest) ----------------
struct TDesc { const float* s; unsigned short* h; unsigned short* l; int K; int N; int off; };
struct TPack { TDesc d[10]; };

__global__ void prep_kernel(TPack p, int nt, const float* __restrict__ x,
                            const float* __restrict__ g, const float* __restrict__ be,
                            unsigned short* __restrict__ xh, unsigned short* __restrict__ xl) {
    __shared__ float tr[32][33];
    __shared__ float red[256];
    int bid = blockIdx.x;
    if (bid < nt) {
        int wi = 0;
#pragma unroll
        for (int i = 1; i < 10; ++i) if (bid >= p.d[i].off) wi = i;
        const TDesc dd = p.d[wi];
        int t = bid - dd.off;
        int ntk = dd.K / 32;
        int tk = t % ntk, tn = t / ntk;
        int k0 = tk * 32, n0 = tn * 32;
        int col = threadIdx.x & 31, rg = threadIdx.x >> 5;   // rg 0..7
#pragma unroll
        for (int i = 0; i < 4; ++i) {
            int row = rg * 4 + i;
            tr[row][col] = dd.s[(size_t)(k0 + row) * dd.N + n0 + col];
        }
        __syncthreads();
#pragma unroll
        for (int i = 0; i < 4; ++i) {
            int n = n0 + rg * 4 + i;
            int k = k0 + col;
            unsigned short h, l;
            split2(tr[col][rg * 4 + i], h, l);
            dd.h[(size_t)n * dd.K + k] = h;
            dd.l[(size_t)n * dd.K + k] = l;
        }
    } else {
        int row = bid - nt;
        int t = threadIdx.x;
        const float* xr = x + (size_t)row * D_;
        float v0 = xr[t], v1 = xr[t + 256];
        red[t] = v0 + v1;
        __syncthreads();
        for (int off = 128; off > 0; off >>= 1) { if (t < off) red[t] += red[t + off]; __syncthreads(); }
        float mean = red[0] * (1.0f / D_);
        __syncthreads();
        float d0 = v0 - mean, d1 = v1 - mean;
        red[t] = d0 * d0 + d1 * d1;
        __syncthreads();
        for (int off = 128; off > 0; off >>= 1) { if (t < off) red[t] += red[t + off]; __syncthreads(); }
        float rs = rsqrtf(red[0] * (1.0f / D_) + 1e-5f);
        float o0 = d0 * rs * g[t] + be[t];
        float o1 = d1 * rs * g[t + 256] + be[t + 256];
        unsigned short h, l;
        split2(o0, h, l); xh[(size_t)row * D_ + t] = h;       xl[(size_t)row * D_ + t] = l;
        split2(o1, h, l); xh[(size_t)row * D_ + t + 256] = h; xl[(size_t)row * D_ + t + 256] = l;
    }
}

// ---------------- MFMA bf16x3 GEMM core: async global_load_lds staging, double-buffered ----------------
struct GemmLds {                       // unpadded (global_load_lds needs linear dest)
    unsigned short A[2][2][64][32];    // [buf][hi/lo][row][k]
    unsigned short B[2][2][64][32];
};                                     // 32768 bytes

__device__ __forceinline__ void gload16(const unsigned short* g, unsigned short* l) {
    __builtin_amdgcn_global_load_lds(
        (const __attribute__((address_space(1))) void*)g,
        (__attribute__((address_space(3))) void*)l, 16, 0, 0);
}

__device__ __forceinline__ void mgemm_core(const unsigned short* __restrict__ Ath,
                                           const unsigned short* __restrict__ Atl,
                                           const unsigned short* __restrict__ Bth,
                                           const unsigned short* __restrict__ Btl,
                                           int K, int rowBase, int colBase,
                                           int kStart, int nsteps,
                                           f32x4 acc[2][2], GemmLds* L) {
    int tid = threadIdx.x;
    int w = tid >> 6, lane = tid & 63;
    int lm = lane & 15, quad = lane >> 4;
    int wm = (w & 1) * 32, wn = (w >> 1) * 32;
    int rS = tid >> 2, kcS = (tid & 3) * 8;   // thread's 16B chunk: row rS, cols kcS..kcS+7
    int wb = w * 512;                          // wave's ushort offset: lds dest = base + wb + lane*8
    size_t aoff = (size_t)(rowBase + rS) * K + kStart + kcS;
    size_t boff = (size_t)(colBase + rS) * K + kStart + kcS;
    // prologue: stage buf 0
    gload16(&Ath[aoff], &L->A[0][0][0][0] + wb);
    gload16(&Atl[aoff], &L->A[0][1][0][0] + wb);
    gload16(&Bth[boff], &L->B[0][0][0][0] + wb);
    gload16(&Btl[boff], &L->B[0][1][0][0] + wb);
    __syncthreads();                           // vmcnt drain: buf0 ready
    for (int s = 0; s < nsteps; ++s) {
        int p = s & 1;
        if (s + 1 < nsteps) {                  // issue next-tile DMA; progresses under MFMAs
            int pn = p ^ 1;
            size_t ao = aoff + (size_t)(s + 1) * 32;
            size_t bo = boff + (size_t)(s + 1) * 32;
            gload16(&Ath[ao], &L->A[pn][0][0][0] + wb);
            gload16(&Atl[ao], &L->A[pn][1][0][0] + wb);
            gload16(&Bth[bo], &L->B[pn][0][0][0] + wb);
            gload16(&Btl[bo], &L->B[pn][1][0][0] + wb);
        }
        short8 ah[2], al[2], bh[2], bl[2];
#pragma unroll
        for (int t = 0; t < 2; ++t) {
            ah[t] = *(const short8*)&L->A[p][0][wm + t * 16 + lm][quad * 8];
            al[t] = *(const short8*)&L->A[p][1][wm + t * 16 + lm][quad * 8];
            bh[t] = *(const short8*)&L->B[p][0][wn + t * 16 + lm][quad * 8];
            bl[t] = *(const short8*)&L->B[p][1][wn + t * 16 + lm][quad * 8];
        }
#pragma unroll
        for (int tm = 0; tm < 2; ++tm)
#pragma unroll
            for (int tn = 0; tn < 2; ++tn) {
                acc[tm][tn] = __builtin_amdgcn_mfma_f32_16x16x32_bf16(ah[tm], bh[tn], acc[tm][tn], 0, 0, 0);
                acc[tm][tn] = __builtin_amdgcn_mfma_f32_16x16x32_bf16(ah[tm], bl[tn], acc[tm][tn], 0, 0, 0);
                acc[tm][tn] = __builtin_amdgcn_mfma_f32_16x16x32_bf16(al[tm], bh[tn], acc[tm][tn], 0, 0, 0);
            }
        __syncthreads();                       // drains next-tile DMA + protects buffer reuse
    }
}

// Generic GEMM: optional fp32 out, optional pre-split bf16 h/l out.
__global__ __launch_bounds__(256) void mgemm_kernel(const unsigned short* __restrict__ Ath,
                                                    const unsigned short* __restrict__ Atl,
                                                    const unsigned short* __restrict__ Bth,
                                                    const unsigned short* __restrict__ Btl,
                                                    const float* __restrict__ bias,
                                                    float* __restrict__ Cf,
                                                    unsigned short* __restrict__ Ch,
                                                    unsigned short* __restrict__ Cl,
                                                    int N, int K, int relu) {
    __shared__ GemmLds L;
    int tid = threadIdx.x;
    int w = tid >> 6, lane = tid & 63;
    int lm = lane & 15, quad = lane >> 4;
    int wm = (w & 1) * 32, wn = (w >> 1) * 32;
    int rowBase = blockIdx.y * 64, colBase = blockIdx.x * 64;
    f32x4 acc[2][2] = {};
    mgemm_core(Ath, Atl, Bth, Btl, K, rowBase, colBase, 0, K / 32, acc, &L);
#pragma unroll
    for (int tm = 0; tm < 2; ++tm)
#pragma unroll
        for (int tn = 0; tn < 2; ++tn) {
            int col = colBase + wn + tn * 16 + lm;
            float bi = bias ? bias[col] : 0.f;
#pragma unroll
            for (int r = 0; r < 4; ++r) {
                int row = rowBase + wm + tm * 16 + quad * 4 + r;
                float v = acc[tm][tn][r] + bi;
                if (relu) v = fmaxf(v, 0.f);
                size_t o = (size_t)row * N + col;
                if (Cf) Cf[o] = v;
                if (Ch) {
                    unsigned short sh, sl;
                    split2(v, sh, sl);
                    Ch[o] = sh; Cl[o] = sl;
                }
            }
        }
}

// z-batched GEMM over weight slabs (QKV: 3, rc halves: 2); fp32 out only.
__global__ __launch_bounds__(256) void mgemm_zw_kernel(const unsigned short* __restrict__ Ath,
                                                       const unsigned short* __restrict__ Atl,
                                                       const unsigned short* __restrict__ Bth,
                                                       const unsigned short* __restrict__ Btl,
                                                       const float* __restrict__ b0,
                                                       const float* __restrict__ b1,
                                                       const float* __restrict__ b2,
                                                       float* __restrict__ Cbase,
                                                       int M, int N, int K) {
    __shared__ GemmLds L;
    int z = blockIdx.z;
    const unsigned short* bth = Bth + (size_t)z * K * N;
    const unsigned short* btl = Btl + (size_t)z * K * N;
    const float* bias = (z == 0) ? b0 : (z == 1) ? b1 : b2;
    float* C = Cbase + (size_t)z * M * N;
    int tid = threadIdx.x;
    int w = tid >> 6, lane = tid & 63;
    int lm = lane & 15, quad = lane >> 4;
    int wm = (w & 1) * 32, wn = (w >> 1) * 32;
    int rowBase = blockIdx.y * 64, colBase = blockIdx.x * 64;
    f32x4 acc[2][2] = {};
    mgemm_core(Ath, Atl, bth, btl, K, rowBase, colBase, 0, K / 32, acc, &L);
#pragma unroll
    for (int tm = 0; tm < 2; ++tm)
#pragma unroll
        for (int tn = 0; tn < 2; ++tn) {
            int col = colBase + wn + tn * 16 + lm;
            float bi = bias ? bias[col] : 0.f;
#pragma unroll
            for (int r = 0; r < 4; ++r) {
                int row = rowBase + wm + tm * 16 + quad * 4 + r;
                C[(size_t)row * N + col] = acc[tm][tn][r] + bi;
            }
        }
}

// split-K partial GEMM: each z-slice writes its own fp32 slab (no atomics).
__global__ __launch_bounds__(256) void mgemm_part_kernel(const unsigned short* __restrict__ Ath,
                                                         const unsigned short* __restrict__ Atl,
                                                         const unsigned short* __restrict__ Bth,
                                                         const unsigned short* __restrict__ Btl,
                                                         float* __restrict__ Cbase,
                                                         int M, int N, int K) {
    __shared__ GemmLds L;
    int ks = gridDim.z, z = blockIdx.z;
    int kLen = K / ks, kStart = z * kLen;
    float* C = Cbase + (size_t)z * M * N;
    int tid = threadIdx.x;
    int w = tid >> 6, lane = tid & 63;
    int lm = lane & 15, quad = lane >> 4;
    int wm = (w & 1) * 32, wn = (w >> 1) * 32;
    int rowBase = blockIdx.y * 64, colBase = blockIdx.x * 64;
    f32x4 acc[2][2] = {};
    mgemm_core(Ath, Atl, Bth, Btl, K, rowBase, colBase, kStart, kLen / 32, acc, &L);
#pragma unroll
    for (int tm = 0; tm < 2; ++tm)
#pragma unroll
        for (int tn = 0; tn < 2; ++tn) {
            int col = colBase + wn + tn * 16 + lm;
#pragma unroll
            for (int r = 0; r < 4; ++r) {
                int row = rowBase + wm + tm * 16 + quad * 4 + r;
                C[(size_t)row * N + col] = acc[tm][tn][r];
            }
        }
}

// sum 4 partials + bias -> nu fp32 + bf16 h/l
__global__ void reduce4_kernel(const float* __restrict__ part, const float* __restrict__ b2,
                               float* __restrict__ nu,
                               unsigned short* __restrict__ nh, unsigned short* __restrict__ nl) {
    int base = blockIdx.x * 1024 + threadIdx.x * 4;
    f32x4 s = *(const f32x4*)&b2[base & (D_ - 1)];
#pragma unroll
    for (int z = 0; z < 4; ++z) s += *(const f32x4*)&part[(size_t)z * BSD_ + base];
    *(f32x4*)&nu[base] = s;
    ushort4v hv, lv;
#pragma unroll
    for (int i = 0; i < 4; ++i) { unsigned short h, l; split2(s[i], h, l); hv[i] = h; lv[i] = l; }
    *(ushort4v*)&nh[base] = hv;
    *(ushort4v*)&nl[base] = lv;
}

// reasoned = nu + sum 8 partials -> bf16 h/l only
__global__ void reduce8_kernel(const float* __restrict__ part, const float* __restrict__ nu,
                               unsigned short* __restrict__ rh, unsigned short* __restrict__ rl) {
    int base = blockIdx.x * 1024 + threadIdx.x * 4;
    f32x4 s = *(const f32x4*)&nu[base];
#pragma unroll
    for (int z = 0; z < 8; ++z) s += *(const f32x4*)&part[(size_t)z * BSD_ + base];
    ushort4v hv, lv;
#pragma unroll
    for (int i = 0; i < 4; ++i) { unsigned short h, l; split2(s[i], h, l); hv[i] = h; lv[i] = l; }
    *(ushort4v*)&rh[base] = hv;
    *(ushort4v*)&rl[base] = lv;
}

// ---------------- Fused attention + adjacency: one block per (b,i), 8 waves = 8 heads ----------------
__global__ __launch_bounds__(512) void attn_fused_kernel(const float* __restrict__ q,
                                                         const float* __restrict__ k,
                                                         const float* __restrict__ v,
                                                         unsigned short* __restrict__ ch,
                                                         unsigned short* __restrict__ cl,
                                                         int* __restrict__ ecount,
                                                         int* __restrict__ elist) {
    __shared__ float qsm[H_][DH_];
    __shared__ float psm[H_][S_];
    int h = threadIdx.x >> 6, lane = threadIdx.x & 63;
    int blk = blockIdx.x;                 // b*S + i
    int i = blk & (S_ - 1);
    int b = blk >> 7;
    const float* qrow = q + (size_t)(b * S_ + i) * D_ + h * DH_;
    qsm[h][lane] = qrow[lane];
    __syncthreads();
    // two scores per lane: j = lane, lane+64
    float s0 = 0.f, s1 = 0.f;
    const float* k0p = k + (size_t)(b * S_ + lane) * D_ + h * DH_;
    const float* k1p = k0p + (size_t)64 * D_;
#pragma unroll 8
    for (int d = 0; d < DH_; ++d) {
        float qd = qsm[h][d];
        s0 += qd * k0p[d];
        s1 += qd * k1p[d];
    }
    s0 *= 0.125f; s1 *= 0.125f;
    float m = fmaxf(s0, s1);
#pragma unroll
    for (int off = 32; off > 0; off >>= 1) m = fmaxf(m, __shfl_xor(m, off));
    float e0 = __expf(s0 - m), e1 = __expf(s1 - m);
    float sum = e0 + e1;
#pragma unroll
    for (int off = 32; off > 0; off >>= 1) sum += __shfl_xor(sum, off);
    float inv = 1.f / sum;
    psm[h][lane] = e0 * inv;
    psm[h][lane + 64] = e1 * inv;
    __syncthreads();
    // adjacency: threads 0..127 handle j = tid
    if (threadIdx.x < S_) {
        int j = threadIdx.x;
        float s = 0.f;
#pragma unroll
        for (int hh = 0; hh < H_; ++hh) s += psm[hh][j];
        s *= (1.0f / H_);
        if (s > 0.1f && i != j) {
            int p = atomicAdd(ecount, 1);
            elist[p] = blk * S_ + j;
        }
    }
    // ctx: lane = d within this head
    const float* vbase = v + (size_t)b * S_ * D_ + h * DH_ + lane;
    float acc = 0.f;
    for (int j = 0; j < S_; ++j) acc += psm[h][j] * vbase[(size_t)j * D_];
    unsigned short sh, sl;
    split2(acc, sh, sl);
    size_t o = (size_t)(b * S_ + i) * D_ + h * DH_ + lane;
    ch[o] = sh; cl[o] = sl;
}

// ---------------- Relation classifier over compacted edges (4 edge-waves per block) ----------------
__global__ __launch_bounds__(256) void edge_kernel(const float* __restrict__ a_part,
                                                   const float* __restrict__ b_part,
                                                   const float* __restrict__ rc_b1,
                                                   const float* __restrict__ rc_w2,
                                                   const float* __restrict__ rc_b2,
                                                   const int* __restrict__ elist,
                                                   const int* __restrict__ ecount,
                                                   int* __restrict__ rel) {
    int w = threadIdx.x >> 6, lane = threadIdx.x & 63;
    int n = *ecount;
    for (int e = blockIdx.x * 4 + w; e < n; e += gridDim.x * 4) {
        int idx = elist[e];
        int vv = idx & (S_ - 1);
        int bu = idx >> 7;
        int u = bu & (S_ - 1);
        int b = bu >> 7;
        const float* ap = a_part + (size_t)(b * S_ + u) * D_;
        const float* bp = b_part + (size_t)(b * S_ + vv) * D_;
        float lp[R_];
#pragma unroll
        for (int r = 0; r < R_; ++r) lp[r] = 0.f;
#pragma unroll
        for (int jj = 0; jj < D_ / 64; ++jj) {
            int d = lane + jj * 64;
            float hv = fmaxf(ap[d] + bp[d] + rc_b1[d], 0.f);
#pragma unroll
            for (int r = 0; r < R_; ++r) lp[r] += hv * rc_w2[d * R_ + r];
        }
#pragma unroll
        for (int r = 0; r < R_; ++r) {
#pragma unroll
            for (int off = 32; off > 0; off >>= 1) lp[r] += __shfl_down(lp[r], off);
        }
        if (lane == 0) {
            float best = lp[0] + rc_b2[0];
            int bi = 0;
#pragma unroll
            for (int r = 1; r < R_; ++r) {
                float L = lp[r] + rc_b2[r];
                if (L > best) { best = L; bi = r; }
            }
            rel[idx] = bi;
        }
    }
}

// ---------------- mbuild: LDS accumulate, pre-split write ----------------
__global__ __launch_bounds__(128) void mbuild_kernel(const float* __restrict__ nu,
                                                     const int* __restrict__ rel,
                                                     unsigned short* __restrict__ Mh,
                                                     unsigned short* __restrict__ Ml) {
    __shared__ float acc[R_ * D_];   // 16 KB
    __shared__ int rl[S_];
    int blk = blockIdx.x;            // b*S + v
    int vv = blk & (S_ - 1);
    int b = blk >> 7;
    int t = threadIdx.x;             // 128
    for (int i = t; i < R_ * D_; i += 128) acc[i] = 0.f;
    rl[t] = rel[((size_t)b * S_ + t) * S_ + vv];
    __syncthreads();
    for (int u = 0; u < S_; ++u) {
        int r = rl[u];
        if (r > 0) {
            const float* nurow = nu + (size_t)(b * S_ + u) * D_;
            float* arow = acc + r * D_;
#pragma unroll
            for (int jj = 0; jj < D_ / 128; ++jj) arow[t + jj * 128] += nurow[t + jj * 128];
        }
    }
    __syncthreads();
    unsigned short* Hrow = Mh + (size_t)blk * (R_ * D_);
    unsigned short* Lrow = Ml + (size_t)blk * (R_ * D_);
    for (int i = t; i < R_ * D_; i += 128) {
        unsigned short sh, sl;
        split2(acc[i], sh, sl);
        Hrow[i] = sh; Lrow[i] = sl;
    }
}

// ---------------- LayerNorm 2 -> fp32 out ----------------
__global__ void ln2_kernel(const float* __restrict__ x, const float* __restrict__ y,
                           const float* __restrict__ g, const float* __restrict__ be,
                           float* __restrict__ out) {
    int row = blockIdx.x;
    int t = threadIdx.x;
    __shared__ float red[256];
    float v0 = x[row * D_ + t]       + y[row * D_ + t];
    float v1 = x[row * D_ + t + 256] + y[row * D_ + t + 256];
    red[t] = v0 + v1;
    __syncthreads();
    for (int off = 128; off > 0; off >>= 1) {
        if (t < off) red[t] += red[t + off];
        __syncthreads();
    }
    float mean = red[0] * (1.0f / D_);
    __syncthreads();
    float d0 = v0 - mean, d1 = v1 - mean;
    red[t] = d0 * d0 + d1 * d1;
    __syncthreads();
    for (int off = 128; off > 0; off >>= 1) {
        if (t < off) red[t] += red[t + off];
        __syncthreads();
    }
    float rs = rsqrtf(red[0] * (1.0f / D_) + 1e-5f);
    out[row * D_ + t]       = d0 * rs * g[t]       + be[t];
    out[row * D_ + t + 256] = d1 * rs * g[t + 256] + be[t + 256];
}

extern "C" void kernel_launch(void* const* d_in, const int* in_sizes, int n_in,
                              void* d_out, int out_size, void* d_ws, size_t ws_size,
                              hipStream_t stream) {
    const float* x     = (const float*)d_in[0];
    const float* ln1_g = (const float*)d_in[1];
    const float* ln1_b = (const float*)d_in[2];
    const float* wq    = (const float*)d_in[3];
    const float* bq    = (const float*)d_in[4];
    const float* wk    = (const float*)d_in[5];
    const float* bk    = (const float*)d_in[6];
    const float* wv    = (const float*)d_in[7];
    const float* bv    = (const float*)d_in[8];
    const float* wo    = (const float*)d_in[9];
    const float* bo    = (const float*)d_in[10];
    const float* w1    = (const float*)d_in[11];
    const float* b1    = (const float*)d_in[12];
    const float* w2    = (const float*)d_in[13];
    const float* b2    = (const float*)d_in[14];
    const float* rc_w1 = (const float*)d_in[15];
    const float* rc_b1 = (const float*)d_in[16];
    const float* rc_w2 = (const float*)d_in[17];
    const float* rc_b2 = (const float*)d_in[18];
    const float* kg_w  = (const float*)d_in[19];
    const float* s2n_w = (const float*)d_in[20];
    const float* s2n_b = (const float*)d_in[21];
    const float* ln2_g = (const float*)d_in[22];
    const float* ln2_b = (const float*)d_in[23];
    float* out = (float*)d_out;

    const int BS  = BS_;              // 512
    const int BSD = BSD_;             // 262144

    // ---- Workspace layout ----
    unsigned short* wt = (unsigned short*)d_ws;
    unsigned short* qkv_h = wt;
    unsigned short* qkv_l = wt + 3 * E_;
    unsigned short* wo_h  = wt + 6 * E_;
    unsigned short* wo_l  = wt + 7 * E_;
    unsigned short* w1_h  = wt + 8 * E_;
    unsigned short* w1_l  = wt + 12 * E_;
    unsigned short* w2_h  = wt + 16 * E_;
    unsigned short* w2_l  = wt + 20 * E_;
    unsigned short* rc_h  = wt + 24 * E_;
    unsigned short* rc_l  = wt + 26 * E_;
    unsigned short* kg_h  = wt + 28 * E_;
    unsigned short* kg_l  = wt + 36 * E_;
    unsigned short* s2_h  = wt + 44 * E_;
    unsigned short* s2_l  = wt + 45 * E_;

    // activation bf16 h/l buffers
    unsigned short* xn_h  = wt + 46 * E_;
    unsigned short* xn_l  = xn_h + BSD;
    unsigned short* ctx_h = xn_l + BSD;
    unsigned short* ctx_l = ctx_h + BSD;
    unsigned short* ao_h  = ctx_l + BSD;
    unsigned short* ao_l  = ao_h + BSD;
    unsigned short* hid_h = ao_l + BSD;              // BS*F
    unsigned short* hid_l = hid_h + (size_t)BS * F_;
    unsigned short* nu_h  = hid_l + (size_t)BS * F_;
    unsigned short* nu_l  = nu_h + BSD;
    unsigned short* mb_h  = nu_l + BSD;              // BS*R*D
    unsigned short* mb_l  = mb_h + (size_t)BS * R_ * D_;
    unsigned short* rs_h  = mb_l + (size_t)BS * R_ * D_;
    unsigned short* rs_l  = rs_h + BSD;

    float* fbase  = (float*)(rs_l + BSD);
    float* q      = fbase;                           // q,k,v slabs (3*BSD)
    float* v_     = q + 2 * BSD;
    float* apart  = q + 3 * BSD;                     // a_part,b_part
    float* nu     = apart + 2 * BSD;
    float* y      = nu + BSD;
    float* part4  = y + BSD;                         // 4*BSD
    float* part8  = part4 + 4 * BSD;                 // 8*BSD

    int* rel    = (int*)(part8 + 8 * BSD);
    int* ecount = rel + B_ * S_ * S_;
    int* elist  = ecount + 64;

    // 0a. zero rel + ecount
    hipMemsetAsync(rel, 0, (size_t)(B_ * S_ * S_ + 64) * 4, stream);
    // 0b. transpose+split all weights + LN1 (fused)
    TPack tp;
    int off = 0;
    auto setd = [&](int i, const float* s, unsigned short* h, unsigned short* l, int K, int N) {
        tp.d[i] = TDesc{s, h, l, K, N, off};
        off += (K / 32) * (N / 32);
    };
    setd(0, wq, qkv_h,          qkv_l,          D_, D_);
    setd(1, wk, qkv_h + E_,     qkv_l + E_,     D_, D_);
    setd(2, wv, qkv_h + 2 * E_, qkv_l + 2 * E_, D_, D_);
    setd(3, wo, wo_h, wo_l, D_, D_);
    setd(4, w1, w1_h, w1_l, D_, F_);
    setd(5, w2, w2_h, w2_l, F_, D_);
    setd(6, rc_w1,            rc_h,      rc_l,      D_, D_);
    setd(7, rc_w1 + D_ * D_,  rc_h + E_, rc_l + E_, D_, D_);
    setd(8, kg_w, kg_h, kg_l, R_ * D_, D_);
    setd(9, s2n_w, s2_h, s2_l, D_, D_);
    hipLaunchKernelGGL(prep_kernel, dim3(off + BS), dim3(256), 0, stream, tp, off,
                       x, ln1_g, ln1_b, xn_h, xn_l);

    // 2. QKV (z-batched) -> q,k,v fp32
    hipLaunchKernelGGL(mgemm_zw_kernel, dim3(D_ / 64, BS / 64, 3), dim3(256), 0, stream,
                       xn_h, xn_l, qkv_h, qkv_l, bq, bk, bv, q, BS, D_, D_);
    // 3. attention + adjacency (fused) -> ctx h/l, elist
    hipLaunchKernelGGL(attn_fused_kernel, dim3(BS), dim3(512), 0, stream,
                       q, q + BSD, v_, ctx_h, ctx_l, ecount, elist);
    // 5. wo: ctx -> attn_out h/l
    hipLaunchKernelGGL(mgemm_kernel, dim3(D_ / 64, BS / 64), dim3(256), 0, stream,
                       ctx_h, ctx_l, wo_h, wo_l, bo, (float*)nullptr, ao_h, ao_l, D_, D_, 0);
    // 6. FFN1 (relu): attn_out -> hidden h/l
    hipLaunchKernelGGL(mgemm_kernel, dim3(F_ / 64, BS / 64), dim3(256), 0, stream,
                       ao_h, ao_l, w1_h, w1_l, b1, (float*)nullptr, hid_h, hid_l, F_, D_, 1);
    // 7. FFN2 split-K=4 partials
    hipLaunchKernelGGL(mgemm_part_kernel, dim3(D_ / 64, BS / 64, 4), dim3(256), 0, stream,
                       hid_h, hid_l, w2_h, w2_l, part4, BS, D_, F_);
    // 7b. reduce + bias -> nu fp32 + h/l
    hipLaunchKernelGGL(reduce4_kernel, dim3(BSD / 1024), dim3(256), 0, stream,
                       part4, b2, nu, nu_h, nu_l);
    // 8. rc halves (z-batched) -> a_part,b_part fp32
    hipLaunchKernelGGL(mgemm_zw_kernel, dim3(D_ / 64, BS / 64, 2), dim3(256), 0, stream,
                       nu_h, nu_l, rc_h, rc_l, (const float*)nullptr, (const float*)nullptr,
                       (const float*)nullptr, apart, BS, D_, D_);
    // 9. edges (persistent over compacted list)
    hipLaunchKernelGGL(edge_kernel, dim3(256), dim3(256), 0, stream,
                       apart, apart + BSD, rc_b1, rc_w2, rc_b2, elist, ecount, rel);
    // 10. RGCN aggregate -> Mbuf h/l
    hipLaunchKernelGGL(mbuild_kernel, dim3(BS), dim3(128), 0, stream, nu, rel, mb_h, mb_l);
    // 11. Mbuf @ kg_w split-K=8 partials
    hipLaunchKernelGGL(mgemm_part_kernel, dim3(D_ / 64, BS / 64, 8), dim3(256), 0, stream,
                       mb_h, mb_l, kg_h, kg_l, part8, BS, D_, R_ * D_);
    // 11b. reduce + residual (nu) -> reasoned h/l
    hipLaunchKernelGGL(reduce8_kernel, dim3(BSD / 1024), dim3(256), 0, stream,
                       part8, nu, rs_h, rs_l);
    // 13. s2n: reasoned -> y fp32
    hipLaunchKernelGGL(mgemm_kernel, dim3(D_ / 64, BS / 64), dim3(256), 0, stream,
                       rs_h, rs_l, s2_h, s2_l, s2n_b, y, (unsigned short*)nullptr,
                       (unsigned short*)nullptr, D_, D_, 0);
    // 14. LN2 -> out
    hipLaunchKernelGGL(ln2_kernel, dim3(BS), dim3(256), 0, stream, x, y, ln2_g, ln2_b, out);
}